// Round 1
// baseline (418.520 us; speedup 1.0000x reference)
//
#include <hip/hip_runtime.h>
#include <cstdint>
#include <cstddef>

#define SEQ 4096
#define DM  2048
#define NH  16
#define KVH 4
#define HD  128

typedef short bf16_t;
typedef __attribute__((ext_vector_type(8))) short bf16x8;
typedef __attribute__((ext_vector_type(4))) float f32x4;

__device__ __forceinline__ bf16_t f2b(float f) {
  unsigned u = __builtin_bit_cast(unsigned, f);
  u += 0x7fffu + ((u >> 16) & 1u);          // RNE
  return (bf16_t)(u >> 16);
}
__device__ __forceinline__ float b2f(bf16_t s) {
  unsigned u = ((unsigned)(unsigned short)s) << 16;
  return __builtin_bit_cast(float, u);
}

// async global->LDS, 16B per lane. LDS dest is wave-uniform base + lane*16
// (linear); swizzling is done by permuting the per-lane GLOBAL source.
__device__ __forceinline__ void gload_lds16(const void* gsrc, void* ldst) {
  __builtin_amdgcn_global_load_lds(
      (__attribute__((address_space(1))) void*)gsrc,
      (__attribute__((address_space(3))) void*)ldst, 16, 0, 0);
}

// ---------------- cast x -> bf16 ----------------
__global__ void cast_x_bf16(const float* __restrict__ x, bf16_t* __restrict__ xb, int n4) {
  int i = blockIdx.x * 256 + threadIdx.x;
  if (i >= n4) return;
  float4 v = ((const float4*)x)[i];
  union { bf16_t h[4]; unsigned long long u; } o;
  o.h[0] = f2b(v.x); o.h[1] = f2b(v.y); o.h[2] = f2b(v.z); o.h[3] = f2b(v.w);
  ((unsigned long long*)xb)[i] = o.u;
}

// ---------------- W [K][N] fp32 -> Wt [N][K] bf16 ----------------
__global__ void transpose_cast_w(const float* __restrict__ W, bf16_t* __restrict__ Wt,
                                 int K, int N) {
  __shared__ float tile[32][33];
  int k0 = blockIdx.y * 32, n0 = blockIdx.x * 32;
  int tx = threadIdx.x, ty = threadIdx.y;
#pragma unroll
  for (int dy = 0; dy < 32; dy += 8)
    tile[ty + dy][tx] = W[(size_t)(k0 + ty + dy) * N + n0 + tx];
  __syncthreads();
#pragma unroll
  for (int dy = 0; dy < 32; dy += 8)
    Wt[(size_t)(n0 + ty + dy) * K + k0 + tx] = f2b(tile[tx][ty + dy]);
}

// ---------------- RoPE cos/sin table ----------------
__global__ void rope_tab(float* __restrict__ ct, float* __restrict__ st) {
  int i = blockIdx.x * 256 + threadIdx.x;
  if (i >= SEQ * 64) return;
  int t = i >> 6, j = i & 63;
  float invf = expf(-(float)j * (9.210340371976184f / 64.0f)); // 10000^(-j/64)
  float ang = (float)t * invf;
  ct[i] = cosf(ang);
  st[i] = sinf(ang);
}

// ---------------- in-place RoPE on bf16 Q and K ----------------
__global__ void rope_apply(bf16_t* __restrict__ Qb, bf16_t* __restrict__ KVb,
                           const float* __restrict__ ct, const float* __restrict__ st) {
  int i = blockIdx.x * 256 + threadIdx.x;
  const int qtot = SEQ * NH * 64;
  const int tot = qtot + SEQ * KVH * 64;
  if (i >= tot) return;
  bf16_t* base; int t, j;
  if (i < qtot) {
    t = i >> 10; int rem = i & 1023; int hh = rem >> 6; j = rem & 63;
    base = Qb + (size_t)t * DM + hh * HD;
  } else {
    int i2 = i - qtot;
    t = i2 >> 8; int rem = i2 & 255; int hh = rem >> 6; j = rem & 63;
    base = KVb + (size_t)t * 1024 + hh * HD;   // K half = cols 0..511
  }
  float c = ct[t * 64 + j], s = st[t * 64 + j];
  float x0 = b2f(base[j]);
  float x1 = b2f(base[j + 64]);
  base[j]      = f2b(x0 * c - x1 * s);
  base[j + 64] = f2b(x1 * c + x0 * s);
}

// ---------------- V half of KVb [T][1024] -> Vt [512][T] ----------------
__global__ void transpose_v(const bf16_t* __restrict__ KVb, bf16_t* __restrict__ Vt) {
  __shared__ bf16_t tile[32][33];
  int t0 = blockIdx.y * 32, d0 = blockIdx.x * 32;
  int tx = threadIdx.x, ty = threadIdx.y;
#pragma unroll
  for (int dy = 0; dy < 32; dy += 8)
    tile[ty + dy][tx] = KVb[(size_t)(t0 + ty + dy) * 1024 + 512 + d0 + tx];
  __syncthreads();
#pragma unroll
  for (int dy = 0; dy < 32; dy += 8)
    Vt[(size_t)(d0 + ty + dy) * SEQ + t0 + tx] = tile[tx][ty + dy];
}

// ---------------- GEMM: C[M][N] = A[M][K] * Bt[N][K]^T (+bias) ----------------
// m97 structure: 128x128 tile, BK=64, 4 waves (2x2), global_load_lds w=16,
// XOR chunk-swizzle (pre-swizzled global source, swizzled ds_read).
template <int BIAS>
__global__ __launch_bounds__(256, 2)
void gemm_bt(const bf16_t* __restrict__ A, const bf16_t* __restrict__ Bt,
             void* __restrict__ Cout, const float* __restrict__ bias,
             int M, int N, int K) {
  __shared__ __align__(16) bf16_t ldsA[128 * 64];
  __shared__ __align__(16) bf16_t ldsB[128 * 64];
  const int t = threadIdx.x;
  const int w = t >> 6, l = t & 63;
  const int lg = l >> 4, lr = l & 15;
  const int bm = blockIdx.y, bn = blockIdx.x;
  const int wr = (w >> 1) * 64, wc = (w & 1) * 64;

  f32x4 acc[4][4] = {};

  for (int k0 = 0; k0 < K; k0 += 64) {
    __syncthreads();
#pragma unroll
    for (int i = 0; i < 4; ++i) {
      int idx = i * 256 + t;          // 0..1023, 16B granules
      int row = idx >> 3;             // 8 chunks per 64-col row
      int ch  = (idx & 7) ^ (row & 7);
      gload_lds16(A  + (size_t)(bm * 128 + row) * K + k0 + ch * 8, &ldsA[idx * 8]);
      gload_lds16(Bt + (size_t)(bn * 128 + row) * K + k0 + ch * 8, &ldsB[idx * 8]);
    }
    __syncthreads();
#pragma unroll
    for (int kk = 0; kk < 2; ++kk) {
      bf16x8 af[4], bfr[4];
#pragma unroll
      for (int m = 0; m < 4; ++m) {
        int row = wr + m * 16 + lr;
        int ch = (kk * 4 + lg) ^ (row & 7);
        af[m] = *(const bf16x8*)&ldsA[row * 64 + ch * 8];
      }
#pragma unroll
      for (int n = 0; n < 4; ++n) {
        int row = wc + n * 16 + lr;
        int ch = (kk * 4 + lg) ^ (row & 7);
        bfr[n] = *(const bf16x8*)&ldsB[row * 64 + ch * 8];
      }
#pragma unroll
      for (int m = 0; m < 4; ++m)
#pragma unroll
        for (int n = 0; n < 4; ++n)
          acc[m][n] = __builtin_amdgcn_mfma_f32_16x16x32_bf16(af[m], bfr[n], acc[m][n], 0, 0, 0);
    }
  }

  // D layout: col = lane&15, row = (lane>>4)*4 + r  [measured m89]
  const int row0 = bm * 128 + wr + lg * 4;
  const int col0 = bn * 128 + wc + lr;
  if (BIAS) {
    float* C = (float*)Cout;
#pragma unroll
    for (int n = 0; n < 4; ++n) {
      int col = col0 + n * 16;
      float b = bias[col];
#pragma unroll
      for (int m = 0; m < 4; ++m)
#pragma unroll
        for (int r = 0; r < 4; ++r)
          C[(size_t)(row0 + m * 16 + r) * N + col] = acc[m][n][r] + b;
    }
  } else {
    bf16_t* C = (bf16_t*)Cout;
#pragma unroll
    for (int m = 0; m < 4; ++m)
#pragma unroll
      for (int n = 0; n < 4; ++n) {
        int col = col0 + n * 16;
#pragma unroll
        for (int r = 0; r < 4; ++r)
          C[(size_t)(row0 + m * 16 + r) * N + col] = f2b(acc[m][n][r]);
      }
  }
}

// ---------------- causal flash attention ----------------
// block = (q-tile of 64 rows, head); 4 waves, 16 q-rows/wave.
__global__ __launch_bounds__(256, 2)
void attn_fwd(const bf16_t* __restrict__ Qb, const bf16_t* __restrict__ KVb,
              const bf16_t* __restrict__ Vt, bf16_t* __restrict__ ctx) {
  __shared__ __align__(16) bf16_t kt[64 * 128];     // K tile, swizzled
  __shared__ __align__(16) bf16_t vts[128 * 64];    // V^T tile, swizzled
  __shared__ __align__(16) bf16_t plds[4][16 * 64]; // per-wave P, swizzled

  const int t = threadIdx.x;
  const int w = t >> 6, l = t & 63;
  const int lg = l >> 4, lr = l & 15;
  const int h = blockIdx.y, g = h >> 2;
  const int q0 = blockIdx.x * 64;

  // Q fragments (A-operand: row = lane&15, k = (lane>>4)*8+i), held in regs
  bf16x8 qf[4];
#pragma unroll
  for (int kk = 0; kk < 4; ++kk)
    qf[kk] = *(const bf16x8*)&Qb[(size_t)(q0 + w * 16 + lr) * DM + h * HD + kk * 32 + lg * 8];

  f32x4 acc_o[8] = {};
  float m_run[4], l_run[4];
#pragma unroll
  for (int r = 0; r < 4; ++r) { m_run[r] = -1e30f; l_run[r] = 0.f; }

  const float sl2e = 0.08838834764831845f * 1.4426950408889634f; // scale*log2(e)

  const int nkv = blockIdx.x + 1;
  for (int kv = 0; kv < nkv; ++kv) {
    const int kv0 = kv * 64;
    __syncthreads();
#pragma unroll
    for (int i = 0; i < 4; ++i) {       // K tile [64][128], 16 chunks/row
      int idx = i * 256 + t;
      int row = idx >> 4;
      int ch = (idx & 15) ^ (row & 7);
      gload_lds16(&KVb[(size_t)(kv0 + row) * 1024 + g * HD + ch * 8], &kt[idx * 8]);
    }
#pragma unroll
    for (int i = 0; i < 4; ++i) {       // V^T tile [128][64], 8 chunks/row
      int idx = i * 256 + t;
      int row = idx >> 3;
      int ch = (idx & 7) ^ (row & 7);
      gload_lds16(&Vt[(size_t)(g * HD + row) * SEQ + kv0 + ch * 8], &vts[idx * 8]);
    }
    __syncthreads();

    // S = Q K^T  (16 q-rows x 64 keys per wave)
    f32x4 s[4];
#pragma unroll
    for (int n = 0; n < 4; ++n) {
      f32x4 a = {0.f, 0.f, 0.f, 0.f};
#pragma unroll
      for (int kk = 0; kk < 4; ++kk) {
        int row = n * 16 + lr;
        int ch = (kk * 4 + lg) ^ (row & 7);
        bf16x8 kf = *(const bf16x8*)&kt[row * 128 + ch * 8];
        a = __builtin_amdgcn_mfma_f32_16x16x32_bf16(qf[kk], kf, a, 0, 0, 0);
      }
      s[n] = a;
    }

    if (kv0 == q0) {                    // diagonal tile: causal mask
#pragma unroll
      for (int n = 0; n < 4; ++n)
#pragma unroll
        for (int r = 0; r < 4; ++r) {
          int key = kv0 + n * 16 + lr;
          int qrow = q0 + w * 16 + lg * 4 + r;
          if (key > qrow) s[n][r] = -1e30f;
        }
    }

    // online softmax (rows live in 16-lane groups; xor-reduce 1,2,4,8)
    float pmax[4];
#pragma unroll
    for (int r = 0; r < 4; ++r)
      pmax[r] = fmaxf(fmaxf(s[0][r], s[1][r]), fmaxf(s[2][r], s[3][r]));
#pragma unroll
    for (int off = 1; off < 16; off <<= 1)
#pragma unroll
      for (int r = 0; r < 4; ++r)
        pmax[r] = fmaxf(pmax[r], __shfl_xor(pmax[r], off, 64));

    float alpha[4], rsum[4];
#pragma unroll
    for (int r = 0; r < 4; ++r) {
      float mn = fmaxf(m_run[r], pmax[r]);
      alpha[r] = exp2f((m_run[r] - mn) * sl2e);
      m_run[r] = mn;
      rsum[r] = 0.f;
    }
#pragma unroll
    for (int n = 0; n < 4; ++n)
#pragma unroll
      for (int r = 0; r < 4; ++r) {
        float p = exp2f((s[n][r] - m_run[r]) * sl2e);
        rsum[r] += p;
        int row = lg * 4 + r;           // D-layout -> P lds (swizzled)
        int col = n * 16 + lr;
        int ch = (col >> 3) ^ (row & 7);
        plds[w][row * 64 + ch * 8 + (col & 7)] = f2b(p);
      }
#pragma unroll
    for (int off = 1; off < 16; off <<= 1)
#pragma unroll
      for (int r = 0; r < 4; ++r)
        rsum[r] += __shfl_xor(rsum[r], off, 64);
#pragma unroll
    for (int r = 0; r < 4; ++r)
      l_run[r] = l_run[r] * alpha[r] + rsum[r];
#pragma unroll
    for (int nd = 0; nd < 8; ++nd)
#pragma unroll
      for (int r = 0; r < 4; ++r)
        acc_o[nd][r] *= alpha[r];

    // O += P * V  (P A-frags from per-wave LDS, V^T B-frags 16B reads)
#pragma unroll
    for (int kk2 = 0; kk2 < 2; ++kk2) {
      int ch = (kk2 * 4 + lg) ^ (lr & 7);
      bf16x8 pf = *(const bf16x8*)&plds[w][lr * 64 + ch * 8];
#pragma unroll
      for (int nd = 0; nd < 8; ++nd) {
        int vrow = nd * 16 + lr;
        int vch = (kk2 * 4 + lg) ^ (vrow & 7);
        bf16x8 vf = *(const bf16x8*)&vts[vrow * 64 + vch * 8];
        acc_o[nd] = __builtin_amdgcn_mfma_f32_16x16x32_bf16(pf, vf, acc_o[nd], 0, 0, 0);
      }
    }
  }

#pragma unroll
  for (int nd = 0; nd < 8; ++nd)
#pragma unroll
    for (int r = 0; r < 4; ++r) {
      int qrow = q0 + w * 16 + lg * 4 + r;
      int col = h * HD + nd * 16 + lr;
      ctx[(size_t)qrow * DM + col] = f2b(acc_o[nd][r] / l_run[r]);
    }
}

extern "C" void kernel_launch(void* const* d_in, const int* in_sizes, int n_in,
                              void* d_out, int out_size, void* d_ws, size_t ws_size,
                              hipStream_t stream) {
  const float* x  = (const float*)d_in[0];
  const float* Wq = (const float*)d_in[1];
  const float* Wk = (const float*)d_in[2];
  const float* Wv = (const float*)d_in[3];
  const float* Wo = (const float*)d_in[4];
  const float* bo = (const float*)d_in[5];
  float* out = (float*)d_out;

  char* p = (char*)d_ws;
  bf16_t* xb   = (bf16_t*)p;                          // also reused as ctx later
  bf16_t* ctx  = xb;                                  // xb dead after KV GEMM
  p += (size_t)SEQ * DM * 2;                          // 16.8 MB
  bf16_t* Wqt  = (bf16_t*)p; p += (size_t)DM * DM * 2;        // 8.4 MB
  bf16_t* Wkvt = (bf16_t*)p; p += (size_t)1024 * DM * 2;      // 4.2 MB
  bf16_t* Wot  = (bf16_t*)p; p += (size_t)DM * DM * 2;        // 8.4 MB
  bf16_t* Qb   = (bf16_t*)p; p += (size_t)SEQ * DM * 2;       // 16.8 MB
  bf16_t* KVb  = (bf16_t*)p; p += (size_t)SEQ * 1024 * 2;     // 8.4 MB
  bf16_t* Vt   = (bf16_t*)p; p += (size_t)512 * SEQ * 2;      // 4.2 MB
  float*  ctab = (float*)p;  p += (size_t)SEQ * 64 * 4;       // 1 MB
  float*  stab = (float*)p;  p += (size_t)SEQ * 64 * 4;       // 1 MB
  // total ~69 MB of d_ws

  // 1. casts / transposes
  cast_x_bf16<<<(SEQ * DM / 4 + 255) / 256, 256, 0, stream>>>(x, xb, SEQ * DM / 4);
  transpose_cast_w<<<dim3(DM / 32, DM / 32), dim3(32, 8), 0, stream>>>(Wq, Wqt, DM, DM);
  transpose_cast_w<<<dim3(512 / 32, DM / 32), dim3(32, 8), 0, stream>>>(Wk, Wkvt, DM, 512);
  transpose_cast_w<<<dim3(512 / 32, DM / 32), dim3(32, 8), 0, stream>>>(Wv, Wkvt + (size_t)512 * DM, DM, 512);
  transpose_cast_w<<<dim3(DM / 32, DM / 32), dim3(32, 8), 0, stream>>>(Wo, Wot, DM, DM);
  rope_tab<<<(SEQ * 64 + 255) / 256, 256, 0, stream>>>(ctab, stab);

  // 2. projections
  gemm_bt<0><<<dim3(DM / 128, SEQ / 128), 256, 0, stream>>>(xb, Wqt, Qb, nullptr, SEQ, DM, DM);
  gemm_bt<0><<<dim3(1024 / 128, SEQ / 128), 256, 0, stream>>>(xb, Wkvt, KVb, nullptr, SEQ, 1024, DM);

  // 3. RoPE + V transpose
  rope_apply<<<(SEQ * (NH + KVH) * 64 + 255) / 256, 256, 0, stream>>>(Qb, KVb, ctab, stab);
  transpose_v<<<dim3(512 / 32, SEQ / 32), dim3(32, 8), 0, stream>>>(KVb, Vt);

  // 4. attention (ctx aliases xb region — xb no longer needed)
  attn_fwd<<<dim3(SEQ / 64, NH), 256, 0, stream>>>(Qb, KVb, Vt, ctx);

  // 5. output projection + bias
  gemm_bt<1><<<dim3(DM / 128, SEQ / 128), 256, 0, stream>>>(ctx, Wot, out, bo, SEQ, DM, DM);
}